// Round 2
// baseline (8299.080 us; speedup 1.0000x reference)
//
#include <hip/hip_runtime.h>
#include <cstdint>
#include <cstddef>

#define TT 4096
#define BB 256

__device__ __forceinline__ float rdlane_f(float v, int l) {
    return __int_as_float(__builtin_amdgcn_readlane(__float_as_int(v), l));
}

// gix[row][g] = b_ih[g] + (g<64 ? b_hh[g] : 0) + sum_{k<64} w_ih[g][k] * x[row][k]
// (b_hh folded for r,z rows; b_hh_n stays in the AR kernel inside r*(.))
__global__ __launch_bounds__(256)
void gix_naive(const float* __restrict__ x, const float* __restrict__ w_ih,
               const float* __restrict__ b_ih, const float* __restrict__ b_hh,
               float* __restrict__ gix) {
    const long long total = (long long)BB * TT * 96;
    long long gid = (long long)blockIdx.x * 256 + threadIdx.x;
    if (gid >= total) return;
    const int row = (int)(gid / 96);
    const int g = (int)(gid - (long long)row * 96);
    const float4* w4 = (const float4*)(w_ih + (size_t)g * 128);
    const float4* x4 = (const float4*)(x + (size_t)row * 64);
    float acc = b_ih[g] + (g < 64 ? b_hh[g] : 0.f);
    float acc2 = 0.f;
#pragma unroll
    for (int k = 0; k < 16; ++k) {
        float4 w = w4[k];
        float4 xv = x4[k];
        acc  = fmaf(w.x, xv.x, acc);
        acc2 = fmaf(w.y, xv.y, acc2);
        acc  = fmaf(w.z, xv.z, acc);
        acc2 = fmaf(w.w, xv.w, acc2);
    }
    gix[gid] = acc + acc2;
}

// Naive-faithful AR loop. One wave per batch element.
// Lane j (= lane&31) owns hidden unit j; lanes 32-63 mirror lanes 0-31.
// Per step: 3x 32-FMA w_hh dots, precise sigmoid/tanh, FC from h_t, argmax,
// gp-table lookup for the emb feedback (exact: linear in emb rows).
template<int MODE>  // 0: x-part from gix ; 1: x-part computed in-loop
__global__ __launch_bounds__(64)
void ar_naive(const float* __restrict__ x,
              const float* __restrict__ w_ih,
              const float* __restrict__ w_hh,
              const float* __restrict__ b_ih,
              const float* __restrict__ b_hh,
              const float* __restrict__ fc_w,
              const float* __restrict__ fc_b,
              const float* __restrict__ emb,
              const float* __restrict__ gix,
              float* __restrict__ out) {
    __shared__ __align__(16) float hsh[32];
    __shared__ __align__(16) float xsh[2][64];
    const int lane = threadIdx.x;
    const int j = lane & 31;
    const int b = blockIdx.x;

    // w_hh rows j (r), 32+j (z), 64+j (n)
    float wr_[32], wz_[32], wn_[32];
    {
        const float4* pr = (const float4*)(w_hh + (size_t)j * 32);
        const float4* pz = (const float4*)(w_hh + (size_t)(32 + j) * 32);
        const float4* pn = (const float4*)(w_hh + (size_t)(64 + j) * 32);
#pragma unroll
        for (int k = 0; k < 8; ++k) {
            float4 a = pr[k]; wr_[4*k]=a.x; wr_[4*k+1]=a.y; wr_[4*k+2]=a.z; wr_[4*k+3]=a.w;
            float4 c = pz[k]; wz_[4*k]=c.x; wz_[4*k+1]=c.y; wz_[4*k+2]=c.z; wz_[4*k+3]=c.w;
            float4 d = pn[k]; wn_[4*k]=d.x; wn_[4*k+1]=d.y; wn_[4*k+2]=d.z; wn_[4*k+3]=d.w;
        }
    }
    // fc row for j<5
    float fw[32];
    float fb = 0.f;
    if (j < 5) {
        const float4* pf = (const float4*)(fc_w + (size_t)j * 32);
#pragma unroll
        for (int k = 0; k < 8; ++k) {
            float4 a = pf[k]; fw[4*k]=a.x; fw[4*k+1]=a.y; fw[4*k+2]=a.z; fw[4*k+3]=a.w;
        }
        fb = fc_b[j];
    } else {
#pragma unroll
        for (int k = 0; k < 32; ++k) fw[k] = 0.f;
    }

    // gp tables: gp?[c] = sum_{k<64} w_ih[row][64+k] * emb[c][k], rows j / 32+j / 64+j
    float gpr[5], gpz[5], gpn[5];
    {
        const float4* qr = (const float4*)(w_ih + (size_t)j * 128 + 64);
        const float4* qz = (const float4*)(w_ih + (size_t)(32 + j) * 128 + 64);
        const float4* qn = (const float4*)(w_ih + (size_t)(64 + j) * 128 + 64);
#pragma unroll
        for (int c = 0; c < 5; ++c) {
            const float4* e4 = (const float4*)(emb + (size_t)c * 64);
            float sr = 0.f, sz = 0.f, sn = 0.f, tr = 0.f, tz = 0.f, tn = 0.f;
#pragma unroll
            for (int k = 0; k < 16; ++k) {
                float4 e = e4[k];
                float4 a = qr[k];
                sr = fmaf(a.x, e.x, sr); tr = fmaf(a.y, e.y, tr);
                sr = fmaf(a.z, e.z, sr); tr = fmaf(a.w, e.w, tr);
                float4 c2 = qz[k];
                sz = fmaf(c2.x, e.x, sz); tz = fmaf(c2.y, e.y, tz);
                sz = fmaf(c2.z, e.z, sz); tz = fmaf(c2.w, e.w, tz);
                float4 d = qn[k];
                sn = fmaf(d.x, e.x, sn); tn = fmaf(d.y, e.y, tn);
                sn = fmaf(d.z, e.z, sn); tn = fmaf(d.w, e.w, tn);
            }
            gpr[c] = sr + tr; gpz[c] = sz + tz; gpn[c] = sn + tn;
        }
    }

    const float bias_n = b_hh[64 + j];

    // MODE1: x-part weights (k<64) for rows j, 32+j, 64+j
    float wxr[64], wxz[64], wxn[64];
    float bxr = 0.f, bxz = 0.f, bxn = 0.f;
    if constexpr (MODE == 1) {
        const float4* qr = (const float4*)(w_ih + (size_t)j * 128);
        const float4* qz = (const float4*)(w_ih + (size_t)(32 + j) * 128);
        const float4* qn = (const float4*)(w_ih + (size_t)(64 + j) * 128);
#pragma unroll
        for (int k = 0; k < 16; ++k) {
            float4 a = qr[k]; wxr[4*k]=a.x; wxr[4*k+1]=a.y; wxr[4*k+2]=a.z; wxr[4*k+3]=a.w;
            float4 c = qz[k]; wxz[4*k]=c.x; wxz[4*k+1]=c.y; wxz[4*k+2]=c.z; wxz[4*k+3]=c.w;
            float4 d = qn[k]; wxn[4*k]=d.x; wxn[4*k+1]=d.y; wxn[4*k+2]=d.z; wxn[4*k+3]=d.w;
        }
        bxr = b_ih[j] + b_hh[j];
        bxz = b_ih[32 + j] + b_hh[32 + j];
        bxn = b_ih[64 + j];
    }

    if (lane < 32) hsh[j] = 0.f;
    float h_reg = 0.f;
    int idx = -1;

    const float* gxp = gix + (size_t)b * TT * 96;
    const float* xgp = x + (size_t)b * TT * 64;
    float* outp = out + (size_t)b * TT * 5;

    float gr_c = 0.f, gz_c = 0.f, gn_c = 0.f;
    if constexpr (MODE == 0) {
        gr_c = gxp[j]; gz_c = gxp[32 + j]; gn_c = gxp[64 + j];
    } else {
        xsh[0][lane] = xgp[lane];
    }

    for (int t = 0; t < TT; ++t) {
        // prefetch step t+1 inputs
        float gr_n = 0.f, gz_n = 0.f, gn_n = 0.f, xv_n = 0.f;
        if (t + 1 < TT) {
            if constexpr (MODE == 0) {
                const float* gnx = gxp + (size_t)(t + 1) * 96;
                gr_n = gnx[j]; gz_n = gnx[32 + j]; gn_n = gnx[64 + j];
            } else {
                xv_n = xgp[(size_t)(t + 1) * 64 + lane];
            }
        }
        // h_{t-1}
        float hf[32];
        {
            const float4* h4 = (const float4*)hsh;
#pragma unroll
            for (int k = 0; k < 8; ++k) {
                float4 a = h4[k];
                hf[4*k]=a.x; hf[4*k+1]=a.y; hf[4*k+2]=a.z; hf[4*k+3]=a.w;
            }
        }
        // w_hh dots
        float ar = 0.f, az = 0.f, an = bias_n;
        float br = 0.f, bz = 0.f, bn = 0.f;
#pragma unroll
        for (int k = 0; k < 32; k += 2) {
            ar = fmaf(wr_[k], hf[k], ar);   br = fmaf(wr_[k+1], hf[k+1], br);
            az = fmaf(wz_[k], hf[k], az);   bz = fmaf(wz_[k+1], hf[k+1], bz);
            an = fmaf(wn_[k], hf[k], an);   bn = fmaf(wn_[k+1], hf[k+1], bn);
        }
        const float ghr = ar + br, ghz = az + bz, ghn = an + bn;

        // x-part
        float gr, gz, gn;
        if constexpr (MODE == 0) {
            gr = gr_c; gz = gz_c; gn = gn_c;
        } else {
            const float4* xb4 = (const float4*)(xsh[t & 1]);
            float ur = bxr, uz = bxz, un = bxn, vr = 0.f, vz = 0.f, vn = 0.f;
#pragma unroll
            for (int k = 0; k < 16; ++k) {
                float4 xv = xb4[k];
                ur = fmaf(wxr[4*k], xv.x, ur); vr = fmaf(wxr[4*k+1], xv.y, vr);
                ur = fmaf(wxr[4*k+2], xv.z, ur); vr = fmaf(wxr[4*k+3], xv.w, vr);
                uz = fmaf(wxz[4*k], xv.x, uz); vz = fmaf(wxz[4*k+1], xv.y, vz);
                uz = fmaf(wxz[4*k+2], xv.z, uz); vz = fmaf(wxz[4*k+3], xv.w, vz);
                un = fmaf(wxn[4*k], xv.x, un); vn = fmaf(wxn[4*k+1], xv.y, vn);
                un = fmaf(wxn[4*k+2], xv.z, un); vn = fmaf(wxn[4*k+3], xv.w, vn);
            }
            gr = ur + vr; gz = uz + vz; gn = un + vn;
        }

        // prev contribution (idx==-1 at t==0 -> zeros)
        const float pr = (idx==0)?gpr[0]:(idx==1)?gpr[1]:(idx==2)?gpr[2]:(idx==3)?gpr[3]:(idx==4)?gpr[4]:0.f;
        const float pz = (idx==0)?gpz[0]:(idx==1)?gpz[1]:(idx==2)?gpz[2]:(idx==3)?gpz[3]:(idx==4)?gpz[4]:0.f;
        const float pn = (idx==0)?gpn[0]:(idx==1)?gpn[1]:(idx==2)?gpn[2]:(idx==3)?gpn[3]:(idx==4)?gpn[4]:0.f;

        // GRU cell, precise math
        const float r = 1.f / (1.f + expf(-(gr + pr + ghr)));
        const float z = 1.f / (1.f + expf(-(gz + pz + ghz)));
        const float n = tanhf(gn + pn + r * ghn);
        const float hnew = (1.f - z) * n + z * h_reg;
        if (lane < 32) hsh[j] = hnew;
        h_reg = hnew;

        // logits from h_t
        float hg[32];
        {
            const float4* h4 = (const float4*)hsh;
#pragma unroll
            for (int k = 0; k < 8; ++k) {
                float4 a = h4[k];
                hg[4*k]=a.x; hg[4*k+1]=a.y; hg[4*k+2]=a.z; hg[4*k+3]=a.w;
            }
        }
        float la = fb, lb = 0.f;
#pragma unroll
        for (int k = 0; k < 32; k += 2) {
            la = fmaf(fw[k], hg[k], la);
            lb = fmaf(fw[k+1], hg[k+1], lb);
        }
        const float lg = la + lb;
        const float l0 = rdlane_f(lg, 0), l1 = rdlane_f(lg, 1), l2 = rdlane_f(lg, 2),
                    l3 = rdlane_f(lg, 3), l4 = rdlane_f(lg, 4);
        const float m = fmaxf(fmaxf(fmaxf(l0, l1), fmaxf(l2, l3)), l4);
        const float ssum = expf(l0-m)+expf(l1-m)+expf(l2-m)+expf(l3-m)+expf(l4-m);
        const float lns = logf(ssum);
        idx = (l0==m)?0:(l1==m)?1:(l2==m)?2:(l3==m)?3:4;
        if (lane < 5) {
            const float lv = (lane==0)?l0:(lane==1)?l1:(lane==2)?l2:(lane==3)?l3:l4;
            outp[(size_t)t * 5 + lane] = (lv - m) - lns;
        }
        if constexpr (MODE == 0) {
            gr_c = gr_n; gz_c = gz_n; gn_c = gn_n;
        } else {
            if (t + 1 < TT) xsh[(t + 1) & 1][lane] = xv_n;
        }
    }
}

extern "C" void kernel_launch(void* const* d_in, const int* in_sizes, int n_in,
                              void* d_out, int out_size, void* d_ws, size_t ws_size,
                              hipStream_t stream) {
    const float* x    = (const float*)d_in[0];
    const float* w_ih = (const float*)d_in[1];
    const float* w_hh = (const float*)d_in[2];
    const float* b_ih = (const float*)d_in[3];
    const float* b_hh = (const float*)d_in[4];
    const float* fc_w = (const float*)d_in[5];
    const float* fc_b = (const float*)d_in[6];
    const float* emb  = (const float*)d_in[7];
    float* out = (float*)d_out;

    const size_t GIX_BYTES = (size_t)BB * TT * 96 * sizeof(float);
    if (ws_size >= GIX_BYTES) {
        float* gix = (float*)d_ws;
        const long long total = (long long)BB * TT * 96;
        const int nblk = (int)((total + 255) / 256);
        gix_naive<<<dim3(nblk), dim3(256), 0, stream>>>(x, w_ih, b_ih, b_hh, gix);
        ar_naive<0><<<dim3(BB), dim3(64), 0, stream>>>(x, w_ih, w_hh, b_ih, b_hh,
                                                       fc_w, fc_b, emb, gix, out);
    } else {
        ar_naive<1><<<dim3(BB), dim3(64), 0, stream>>>(x, w_ih, w_hh, b_ih, b_hh,
                                                       fc_w, fc_b, emb, (const float*)d_ws, out);
    }
}

// Round 3
// 3202.925 us; speedup vs baseline: 2.5911x; 2.5911x over previous
//
#include <hip/hip_runtime.h>
#include <cstdint>
#include <cstddef>

#define TT 4096
#define BB 256

static_assert(TT % 4 == 0, "pipeline unroll assumes TT%4==0");

__device__ __forceinline__ float rdlane_f(float v, int l) {
    return __int_as_float(__builtin_amdgcn_readlane(__float_as_int(v), l));
}

// ---------------- kernel 1: gix precompute (tiled, packed layout) ----------------
// Packed per row (96 floats): [ (r_0,n_0),(r_1,n_1),...,(r_31,n_31) | z_0..z_31 ]
//   r_j = b_ih[j]    + b_hh[j]    + sum_k w_ih[j]   [k] * x[row][k]
//   z_j = b_ih[32+j] + b_hh[32+j] + sum_k w_ih[32+j][k] * x[row][k]
//   n_j = b_ih[64+j] + 0          + sum_k w_ih[64+j][k] * x[row][k]
// Accumulation order matches round-2's gix_naive bitwise (a: .x/.z, c: .y/.w, a+c).
__global__ __launch_bounds__(256, 2)
void gix_fast(const float* __restrict__ x, const float* __restrict__ w_ih,
              const float* __restrict__ b_ih, const float* __restrict__ b_hh,
              float* __restrict__ gix) {
    __shared__ __align__(16) float xt[256 * 64];
    const int tid = threadIdx.x;
    const size_t row0 = (size_t)blockIdx.x * 256;
    {
        const float4* xs = (const float4*)(x + row0 * 64);
        float4* ls = (float4*)xt;
#pragma unroll
        for (int i = 0; i < 16; ++i) ls[tid + i * 256] = xs[tid + i * 256];
    }
    __syncthreads();
    const int lane = tid & 63;
    const int wave = tid >> 6;
    const int j = lane & 31;
    const bool lol = (lane < 32);

    float w0[64], w1[64], w2[64];
    {
        const float4* p0 = (const float4*)(w_ih + (size_t)j * 128);
        const float4* p1 = (const float4*)(w_ih + (size_t)(32 + j) * 128);
        const float4* p2 = (const float4*)(w_ih + (size_t)(64 + j) * 128);
#pragma unroll
        for (int k = 0; k < 16; ++k) {
            float4 a = p0[k]; w0[4*k]=a.x; w0[4*k+1]=a.y; w0[4*k+2]=a.z; w0[4*k+3]=a.w;
            float4 b = p1[k]; w1[4*k]=b.x; w1[4*k+1]=b.y; w1[4*k+2]=b.z; w1[4*k+3]=b.w;
            float4 c = p2[k]; w2[4*k]=c.x; w2[4*k+1]=c.y; w2[4*k+2]=c.z; w2[4*k+3]=c.w;
        }
    }
    const float bias0 = b_ih[j] + b_hh[j];
    const float bias1 = b_ih[32 + j] + b_hh[32 + j];
    const float bias2 = b_ih[64 + j] + 0.f;

    for (int p = 0; p < 32; ++p) {
        const int r = wave * 64 + 2 * p + (lol ? 0 : 1);
        const float4* xr = (const float4*)(xt + r * 64);
        float a0 = bias0, a1 = bias1, a2 = bias2;
        float c0 = 0.f, c1 = 0.f, c2 = 0.f;
#pragma unroll
        for (int k = 0; k < 16; ++k) {
            float4 xv = xr[k];
            a0 = fmaf(w0[4*k],   xv.x, a0); c0 = fmaf(w0[4*k+1], xv.y, c0);
            a0 = fmaf(w0[4*k+2], xv.z, a0); c0 = fmaf(w0[4*k+3], xv.w, c0);
            a1 = fmaf(w1[4*k],   xv.x, a1); c1 = fmaf(w1[4*k+1], xv.y, c1);
            a1 = fmaf(w1[4*k+2], xv.z, a1); c1 = fmaf(w1[4*k+3], xv.w, c1);
            a2 = fmaf(w2[4*k],   xv.x, a2); c2 = fmaf(w2[4*k+1], xv.y, c2);
            a2 = fmaf(w2[4*k+2], xv.z, a2); c2 = fmaf(w2[4*k+3], xv.w, c2);
        }
        float* ob = gix + (row0 + r) * 96;
        float2 rn; rn.x = a0 + c0; rn.y = a2 + c2;      // (r_j, n_j)
        ((float2*)ob)[j] = rn;
        ob[64 + j] = a1 + c1;                           // z_j
    }
}

// ---------------- kernel 2: autoregressive loop (LDS-free) ----------------
// One wave per batch element. h kept as 32 uniform scalars (v_readlane gather).
// slot1: lo lanes r-row j, hi lanes z-row 32+j          (w_hh, K=32)
// slot2: lo lanes n-row 64+j, hi lanes j<5 fc-row j     (deferred FC: logits(h_{t-1}))
// All recurrent-path arithmetic is bitwise-identical to the round-2 passing kernel;
// only the softmax OUTPUT (non-feedback) uses __expf/__logf.
__global__ __launch_bounds__(64, 1)
void ar_fast(const float* __restrict__ w_ih,
             const float* __restrict__ w_hh,
             const float* __restrict__ b_ih,
             const float* __restrict__ b_hh,
             const float* __restrict__ fc_w,
             const float* __restrict__ fc_b,
             const float* __restrict__ emb,
             const float* __restrict__ gix,
             float* __restrict__ out) {
    const int lane = threadIdx.x;
    const int j = lane & 31;
    const bool lol = (lane < 32);
    const int b = blockIdx.x;

    // slot1 weights: lo -> w_hh row j (r), hi -> row 32+j (z)
    float w1[32];
    {
        const float4* ps = (const float4*)(w_hh + (size_t)(lol ? j : 32 + j) * 32);
#pragma unroll
        for (int k = 0; k < 8; ++k) {
            float4 a = ps[k];
            w1[4*k]=a.x; w1[4*k+1]=a.y; w1[4*k+2]=a.z; w1[4*k+3]=a.w;
        }
    }
    // slot2 weights: lo -> w_hh row 64+j (n), hi j<5 -> fc_w row j, else zeros
    float w2[32];
    float a2init;
    if (lol) {
        const float4* pn = (const float4*)(w_hh + (size_t)(64 + j) * 32);
#pragma unroll
        for (int k = 0; k < 8; ++k) {
            float4 a = pn[k];
            w2[4*k]=a.x; w2[4*k+1]=a.y; w2[4*k+2]=a.z; w2[4*k+3]=a.w;
        }
        a2init = b_hh[64 + j];
    } else if (j < 5) {
        const float4* pf = (const float4*)(fc_w + (size_t)j * 32);
#pragma unroll
        for (int k = 0; k < 8; ++k) {
            float4 a = pf[k];
            w2[4*k]=a.x; w2[4*k+1]=a.y; w2[4*k+2]=a.z; w2[4*k+3]=a.w;
        }
        a2init = fc_b[j];
    } else {
#pragma unroll
        for (int k = 0; k < 32; ++k) w2[k] = 0.f;
        a2init = 0.f;
    }

    // gp tables: p1t[c] = w_ih row (lo: j, hi: 32+j), cols 64.., dot emb[c]
    //            p2t[c] = w_ih row 64+j (lo only), cols 64.., dot emb[c]
    float p1t[5], p2t[5];
    {
        const float4* q1 = (const float4*)(w_ih + (size_t)(lol ? j : 32 + j) * 128 + 64);
        const float4* q2 = (const float4*)(w_ih + (size_t)(64 + j) * 128 + 64);
#pragma unroll
        for (int c = 0; c < 5; ++c) {
            const float4* e4 = (const float4*)(emb + (size_t)c * 64);
            float s1 = 0.f, t1 = 0.f, s2 = 0.f, t2 = 0.f;
#pragma unroll
            for (int k = 0; k < 16; ++k) {
                float4 e = e4[k];
                float4 a = q1[k];
                s1 = fmaf(a.x, e.x, s1); t1 = fmaf(a.y, e.y, t1);
                s1 = fmaf(a.z, e.z, s1); t1 = fmaf(a.w, e.w, t1);
                float4 d = q2[k];
                s2 = fmaf(d.x, e.x, s2); t2 = fmaf(d.y, e.y, t2);
                s2 = fmaf(d.z, e.z, s2); t2 = fmaf(d.w, e.w, t2);
            }
            p1t[c] = s1 + t1;
            p2t[c] = lol ? (s2 + t2) : 0.f;
        }
    }

    // state: h as 32 uniform scalars + per-lane h_j (lo lanes)
    float sh[32];
#pragma unroll
    for (int k = 0; k < 32; ++k) sh[k] = 0.f;
    float h_reg = 0.f;
    int idx = -1;

    const float* gxp = gix + (size_t)b * TT * 96;
    float* outp = out + (size_t)b * TT * 5;

    // per-lane gix offset into packed row: lo -> pair (r_j,n_j) at 2j ;
    // hi -> aligned pair of z's at 64+(j&~1), select by j&1.
    const int loff = lol ? (2 * j) : (64 + (j & ~1));
    const bool zodd = (!lol) && (j & 1);

    float2 q0 = *(const float2*)(gxp + (size_t)0 * 96 + loff);
    float2 q1_ = *(const float2*)(gxp + (size_t)1 * 96 + loff);
    float2 q2_ = *(const float2*)(gxp + (size_t)2 * 96 + loff);
    float2 q3_ = *(const float2*)(gxp + (size_t)3 * 96 + loff);

    auto STEP = [&](float2& q, int t, int tld) {
        // slot dots over uniform h (h_{t-1})
        float a1 = 0.f, c1 = 0.f, a2 = a2init, c2 = 0.f;
#pragma unroll
        for (int k = 0; k < 32; k += 2) {
            a1 = fmaf(w1[k],   sh[k],   a1); c1 = fmaf(w1[k+1], sh[k+1], c1);
            a2 = fmaf(w2[k],   sh[k],   a2); c2 = fmaf(w2[k+1], sh[k+1], c2);
        }
        const float gh1 = a1 + c1;   // lo: ghr ; hi: ghz
        const float gh2 = a2 + c2;   // lo: b_hh_n + ghn ; hi j<5: logits_{t-1}[j]

        const float g1 = lol ? q.x : (zodd ? q.y : q.x);  // lo: gix r ; hi: gix z
        const float g2 = lol ? q.y : 0.f;                 // lo: gix n

        // refill pipeline slot (consumed 4 steps from now)
        q = *(const float2*)(gxp + (size_t)tld * 96 + loff);

        // argmax + log-softmax OUTPUT for step t-1 (logits on lanes 32..36)
        if (t > 0) {
            const float l0 = rdlane_f(gh2, 32);
            const float l1 = rdlane_f(gh2, 33);
            const float l2 = rdlane_f(gh2, 34);
            const float l3 = rdlane_f(gh2, 35);
            const float l4 = rdlane_f(gh2, 36);
            const float m = fmaxf(fmaxf(fmaxf(l0, l1), fmaxf(l2, l3)), l4);
            idx = (l0 == m) ? 0 : (l1 == m) ? 1 : (l2 == m) ? 2 : (l3 == m) ? 3 : 4;
            // output-only fast math: logp never feeds back into the trajectory
            const float ssum = __expf(l0 - m) + __expf(l1 - m) + __expf(l2 - m)
                             + __expf(l3 - m) + __expf(l4 - m);
            const float lns = __logf(ssum);
            if (lane < 5) {
                const float lv = (lane == 0) ? l0 : (lane == 1) ? l1 : (lane == 2) ? l2
                               : (lane == 3) ? l3 : l4;
                outp[(size_t)(t - 1) * 5 + lane] = (lv - m) - lns;
            }
        }
        // prev-embedding contribution (idx == -1 at t==0 -> zeros)
        const float p1 = (idx==0)?p1t[0]:(idx==1)?p1t[1]:(idx==2)?p1t[2]:(idx==3)?p1t[3]:(idx==4)?p1t[4]:0.f;
        const float p2 = (idx==0)?p2t[0]:(idx==1)?p2t[1]:(idx==2)?p2t[2]:(idx==3)?p2t[3]:(idx==4)?p2t[4]:0.f;

        // GRU cell — precise math, identical forms to the passing kernel
        const float s1v = 1.f / (1.f + expf(-(g1 + p1 + gh1)));  // lo: r ; hi: z
        const float zz = __shfl_xor(s1v, 32, 64);                // lo receives z
        const float nn = tanhf(g2 + p2 + s1v * gh2);             // lo: n
        const float hnew = (1.f - zz) * nn + zz * h_reg;
        if (lol) h_reg = hnew;

        // gather h_t to uniform scalars (no LDS)
#pragma unroll
        for (int k = 0; k < 32; ++k) sh[k] = rdlane_f(hnew, k);
    };

    for (int t = 0; t < TT; t += 4) {
        STEP(q0,  t,     (t + 4 < TT) ? t + 4 : TT - 1);
        STEP(q1_, t + 1, (t + 5 < TT) ? t + 5 : TT - 1);
        STEP(q2_, t + 2, (t + 6 < TT) ? t + 6 : TT - 1);
        STEP(q3_, t + 3, (t + 7 < TT) ? t + 7 : TT - 1);
    }

    // tail: logits for t = TT-1 from final h
    {
        float a2 = a2init, c2 = 0.f;
#pragma unroll
        for (int k = 0; k < 32; k += 2) {
            a2 = fmaf(w2[k],   sh[k],   a2);
            c2 = fmaf(w2[k+1], sh[k+1], c2);
        }
        const float gh2 = a2 + c2;
        const float l0 = rdlane_f(gh2, 32);
        const float l1 = rdlane_f(gh2, 33);
        const float l2 = rdlane_f(gh2, 34);
        const float l3 = rdlane_f(gh2, 35);
        const float l4 = rdlane_f(gh2, 36);
        const float m = fmaxf(fmaxf(fmaxf(l0, l1), fmaxf(l2, l3)), l4);
        const float ssum = __expf(l0 - m) + __expf(l1 - m) + __expf(l2 - m)
                         + __expf(l3 - m) + __expf(l4 - m);
        const float lns = __logf(ssum);
        if (lane < 5) {
            const float lv = (lane == 0) ? l0 : (lane == 1) ? l1 : (lane == 2) ? l2
                           : (lane == 3) ? l3 : l4;
            outp[(size_t)(TT - 1) * 5 + lane] = (lv - m) - lns;
        }
    }
}

// ---------------- fallback (ws too small): round-2 MODE1, known-correct ----------------
__global__ __launch_bounds__(64)
void ar_fallback(const float* __restrict__ x,
                 const float* __restrict__ w_ih,
                 const float* __restrict__ w_hh,
                 const float* __restrict__ b_ih,
                 const float* __restrict__ b_hh,
                 const float* __restrict__ fc_w,
                 const float* __restrict__ fc_b,
                 const float* __restrict__ emb,
                 float* __restrict__ out) {
    __shared__ __align__(16) float hsh[32];
    __shared__ __align__(16) float xsh[2][64];
    const int lane = threadIdx.x;
    const int j = lane & 31;
    const int b = blockIdx.x;

    float wr_[32], wz_[32], wn_[32];
    {
        const float4* pr = (const float4*)(w_hh + (size_t)j * 32);
        const float4* pz = (const float4*)(w_hh + (size_t)(32 + j) * 32);
        const float4* pn = (const float4*)(w_hh + (size_t)(64 + j) * 32);
#pragma unroll
        for (int k = 0; k < 8; ++k) {
            float4 a = pr[k]; wr_[4*k]=a.x; wr_[4*k+1]=a.y; wr_[4*k+2]=a.z; wr_[4*k+3]=a.w;
            float4 c = pz[k]; wz_[4*k]=c.x; wz_[4*k+1]=c.y; wz_[4*k+2]=c.z; wz_[4*k+3]=c.w;
            float4 d = pn[k]; wn_[4*k]=d.x; wn_[4*k+1]=d.y; wn_[4*k+2]=d.z; wn_[4*k+3]=d.w;
        }
    }
    float fw[32]; float fb = 0.f;
    if (j < 5) {
        const float4* pf = (const float4*)(fc_w + (size_t)j * 32);
#pragma unroll
        for (int k = 0; k < 8; ++k) {
            float4 a = pf[k]; fw[4*k]=a.x; fw[4*k+1]=a.y; fw[4*k+2]=a.z; fw[4*k+3]=a.w;
        }
        fb = fc_b[j];
    } else {
#pragma unroll
        for (int k = 0; k < 32; ++k) fw[k] = 0.f;
    }
    float gpr[5], gpz[5], gpn[5];
    {
        const float4* qr = (const float4*)(w_ih + (size_t)j * 128 + 64);
        const float4* qz = (const float4*)(w_ih + (size_t)(32 + j) * 128 + 64);
        const float4* qn = (const float4*)(w_ih + (size_t)(64 + j) * 128 + 64);
#pragma unroll
        for (int c = 0; c < 5; ++c) {
            const float4* e4 = (const float4*)(emb + (size_t)c * 64);
            float sr = 0.f, sz = 0.f, sn = 0.f, tr = 0.f, tz = 0.f, tn = 0.f;
#pragma unroll
            for (int k = 0; k < 16; ++k) {
                float4 e = e4[k];
                float4 a = qr[k];
                sr = fmaf(a.x, e.x, sr); tr = fmaf(a.y, e.y, tr);
                sr = fmaf(a.z, e.z, sr); tr = fmaf(a.w, e.w, tr);
                float4 c2 = qz[k];
                sz = fmaf(c2.x, e.x, sz); tz = fmaf(c2.y, e.y, tz);
                sz = fmaf(c2.z, e.z, sz); tz = fmaf(c2.w, e.w, tz);
                float4 d = qn[k];
                sn = fmaf(d.x, e.x, sn); tn = fmaf(d.y, e.y, tn);
                sn = fmaf(d.z, e.z, sn); tn = fmaf(d.w, e.w, tn);
            }
            gpr[c] = sr + tr; gpz[c] = sz + tz; gpn[c] = sn + tn;
        }
    }
    const float bias_n = b_hh[64 + j];
    float wxr[64], wxz[64], wxn[64];
    float bxr, bxz, bxn;
    {
        const float4* qr = (const float4*)(w_ih + (size_t)j * 128);
        const float4* qz = (const float4*)(w_ih + (size_t)(32 + j) * 128);
        const float4* qn = (const float4*)(w_ih + (size_t)(64 + j) * 128);
#pragma unroll
        for (int k = 0; k < 16; ++k) {
            float4 a = qr[k]; wxr[4*k]=a.x; wxr[4*k+1]=a.y; wxr[4*k+2]=a.z; wxr[4*k+3]=a.w;
            float4 c = qz[k]; wxz[4*k]=c.x; wxz[4*k+1]=c.y; wxz[4*k+2]=c.z; wxz[4*k+3]=c.w;
            float4 d = qn[k]; wxn[4*k]=d.x; wxn[4*k+1]=d.y; wxn[4*k+2]=d.z; wxn[4*k+3]=d.w;
        }
        bxr = b_ih[j] + b_hh[j];
        bxz = b_ih[32 + j] + b_hh[32 + j];
        bxn = b_ih[64 + j];
    }

    if (lane < 32) hsh[j] = 0.f;
    float h_reg = 0.f;
    int idx = -1;
    const float* xgp = x + (size_t)b * TT * 64;
    float* outp = out + (size_t)b * TT * 5;
    xsh[0][lane] = xgp[lane];

    for (int t = 0; t < TT; ++t) {
        float xv_n = 0.f;
        if (t + 1 < TT) xv_n = xgp[(size_t)(t + 1) * 64 + lane];
        float hf[32];
        {
            const float4* h4 = (const float4*)hsh;
#pragma unroll
            for (int k = 0; k < 8; ++k) {
                float4 a = h4[k];
                hf[4*k]=a.x; hf[4*k+1]=a.y; hf[4*k+2]=a.z; hf[4*k+3]=a.w;
            }
        }
        float ar = 0.f, az = 0.f, an = bias_n;
        float br = 0.f, bz = 0.f, bn = 0.f;
#pragma unroll
        for (int k = 0; k < 32; k += 2) {
            ar = fmaf(wr_[k], hf[k], ar);   br = fmaf(wr_[k+1], hf[k+1], br);
            az = fmaf(wz_[k], hf[k], az);   bz = fmaf(wz_[k+1], hf[k+1], bz);
            an = fmaf(wn_[k], hf[k], an);   bn = fmaf(wn_[k+1], hf[k+1], bn);
        }
        const float ghr = ar + br, ghz = az + bz, ghn = an + bn;
        const float4* xb4 = (const float4*)(xsh[t & 1]);
        float ur = bxr, uz = bxz, un = bxn, vr = 0.f, vz = 0.f, vn = 0.f;
#pragma unroll
        for (int k = 0; k < 16; ++k) {
            float4 xv = xb4[k];
            ur = fmaf(wxr[4*k], xv.x, ur); vr = fmaf(wxr[4*k+1], xv.y, vr);
            ur = fmaf(wxr[4*k+2], xv.z, ur); vr = fmaf(wxr[4*k+3], xv.w, vr);
            uz = fmaf(wxz[4*k], xv.x, uz); vz = fmaf(wxz[4*k+1], xv.y, vz);
            uz = fmaf(wxz[4*k+2], xv.z, uz); vz = fmaf(wxz[4*k+3], xv.w, vz);
            un = fmaf(wxn[4*k], xv.x, un); vn = fmaf(wxn[4*k+1], xv.y, vn);
            un = fmaf(wxn[4*k+2], xv.z, un); vn = fmaf(wxn[4*k+3], xv.w, vn);
        }
        const float gr = ur + vr, gz = uz + vz, gn = un + vn;
        const float pr = (idx==0)?gpr[0]:(idx==1)?gpr[1]:(idx==2)?gpr[2]:(idx==3)?gpr[3]:(idx==4)?gpr[4]:0.f;
        const float pz = (idx==0)?gpz[0]:(idx==1)?gpz[1]:(idx==2)?gpz[2]:(idx==3)?gpz[3]:(idx==4)?gpz[4]:0.f;
        const float pn = (idx==0)?gpn[0]:(idx==1)?gpn[1]:(idx==2)?gpn[2]:(idx==3)?gpn[3]:(idx==4)?gpn[4]:0.f;
        const float r = 1.f / (1.f + expf(-(gr + pr + ghr)));
        const float z = 1.f / (1.f + expf(-(gz + pz + ghz)));
        const float n = tanhf(gn + pn + r * ghn);
        const float hnew = (1.f - z) * n + z * h_reg;
        if (lane < 32) hsh[j] = hnew;
        h_reg = hnew;
        float hg[32];
        {
            const float4* h4 = (const float4*)hsh;
#pragma unroll
            for (int k = 0; k < 8; ++k) {
                float4 a = h4[k];
                hg[4*k]=a.x; hg[4*k+1]=a.y; hg[4*k+2]=a.z; hg[4*k+3]=a.w;
            }
        }
        float la = fb, lb = 0.f;
#pragma unroll
        for (int k = 0; k < 32; k += 2) {
            la = fmaf(fw[k], hg[k], la);
            lb = fmaf(fw[k+1], hg[k+1], lb);
        }
        const float lg = la + lb;
        const float l0 = rdlane_f(lg, 0), l1 = rdlane_f(lg, 1), l2 = rdlane_f(lg, 2),
                    l3 = rdlane_f(lg, 3), l4 = rdlane_f(lg, 4);
        const float m = fmaxf(fmaxf(fmaxf(l0, l1), fmaxf(l2, l3)), l4);
        const float ssum = expf(l0-m)+expf(l1-m)+expf(l2-m)+expf(l3-m)+expf(l4-m);
        const float lns = logf(ssum);
        idx = (l0==m)?0:(l1==m)?1:(l2==m)?2:(l3==m)?3:4;
        if (lane < 5) {
            const float lv = (lane==0)?l0:(lane==1)?l1:(lane==2)?l2:(lane==3)?l3:l4;
            outp[(size_t)t * 5 + lane] = (lv - m) - lns;
        }
        if (t + 1 < TT) xsh[(t + 1) & 1][lane] = xv_n;
    }
}

extern "C" void kernel_launch(void* const* d_in, const int* in_sizes, int n_in,
                              void* d_out, int out_size, void* d_ws, size_t ws_size,
                              hipStream_t stream) {
    const float* x    = (const float*)d_in[0];
    const float* w_ih = (const float*)d_in[1];
    const float* w_hh = (const float*)d_in[2];
    const float* b_ih = (const float*)d_in[3];
    const float* b_hh = (const float*)d_in[4];
    const float* fc_w = (const float*)d_in[5];
    const float* fc_b = (const float*)d_in[6];
    const float* emb  = (const float*)d_in[7];
    float* out = (float*)d_out;

    const size_t GIX_BYTES = (size_t)BB * TT * 96 * sizeof(float);
    if (ws_size >= GIX_BYTES) {
        float* gix = (float*)d_ws;
        gix_fast<<<dim3((BB * TT) / 256), dim3(256), 0, stream>>>(x, w_ih, b_ih, b_hh, gix);
        ar_fast<<<dim3(BB), dim3(64), 0, stream>>>(w_ih, w_hh, b_ih, b_hh,
                                                   fc_w, fc_b, emb, gix, out);
    } else {
        ar_fallback<<<dim3(BB), dim3(64), 0, stream>>>(x, w_ih, w_hh, b_ih, b_hh,
                                                       fc_w, fc_b, emb, out);
    }
}

// Round 7
// 3124.790 us; speedup vs baseline: 2.6559x; 1.0250x over previous
//
#include <hip/hip_runtime.h>
#include <cstdint>
#include <cstddef>

#define TT 4096
#define BB 256

static_assert(TT % 4 == 0, "pipeline unroll assumes TT%4==0");

__device__ __forceinline__ float rdlane_f(float v, int l) {
    return __int_as_float(__builtin_amdgcn_readlane(__float_as_int(v), l));
}

// Branch-free high-accuracy expf (~1.5 ulp) for bounded args (|x| < ~80).
// Cody-Waite 2-term reduction keeps the exponent-arg rounding error ~2^-25.
__device__ __forceinline__ float exp_cw(float x) {
    const float L2E = 1.4426950408889634f;
    float n = rintf(x * L2E);                 // v_rndne
    float r = fmaf(n, -0.693359375f, x);      // C1 = 355/512 (9-bit mantissa, exact prods)
    r = fmaf(n, 2.12194440e-4f, r);           // C2 = C1 - ln2
    float g = __builtin_amdgcn_exp2f(r * L2E);  // v_exp_f32, |arg| <= 0.5
    return g * __int_as_float(((int)n + 127) << 23);  // * 2^n (n in [-70,70])
}

// NR-refined reciprocal (~1 ulp).
__device__ __forceinline__ float rcp_nr(float d) {
    float y = __builtin_amdgcn_rcpf(d);
    return y * fmaf(-d, y, 2.f);
}

__device__ __forceinline__ float sigmoid_fast(float x) {
    float e = exp_cw(-x);
    return rcp_nr(1.f + e);
}

// tanh(a) = (e^{2a}-1)/(e^{2a}+1); numerator subtraction is Sterbenz-exact
// near 1 so absolute error stays ~1e-7 even for small a. Branch-free.
__device__ __forceinline__ float tanh_fast(float a) {
    float e = exp_cw(2.f * a);
    return (e - 1.f) * rcp_nr(e + 1.f);
}

// ---------------- kernel 1: gix precompute (tiled, packed layout) ----------------
// Packed per row (96 floats): [ (r_0,n_0),(r_1,n_1),...,(r_31,n_31) | z_0..z_31 ]
__global__ __launch_bounds__(256, 2)
void gix_fast(const float* __restrict__ x, const float* __restrict__ w_ih,
              const float* __restrict__ b_ih, const float* __restrict__ b_hh,
              float* __restrict__ gix) {
    __shared__ __align__(16) float xt[256 * 64];
    const int tid = threadIdx.x;
    const size_t row0 = (size_t)blockIdx.x * 256;
    {
        const float4* xs = (const float4*)(x + row0 * 64);
        float4* ls = (float4*)xt;
#pragma unroll
        for (int i = 0; i < 16; ++i) ls[tid + i * 256] = xs[tid + i * 256];
    }
    __syncthreads();
    const int lane = tid & 63;
    const int wave = tid >> 6;
    const int j = lane & 31;
    const bool lol = (lane < 32);

    float w0[64], w1[64], w2[64];
    {
        const float4* p0 = (const float4*)(w_ih + (size_t)j * 128);
        const float4* p1 = (const float4*)(w_ih + (size_t)(32 + j) * 128);
        const float4* p2 = (const float4*)(w_ih + (size_t)(64 + j) * 128);
#pragma unroll
        for (int k = 0; k < 16; ++k) {
            float4 a = p0[k]; w0[4*k]=a.x; w0[4*k+1]=a.y; w0[4*k+2]=a.z; w0[4*k+3]=a.w;
            float4 b = p1[k]; w1[4*k]=b.x; w1[4*k+1]=b.y; w1[4*k+2]=b.z; w1[4*k+3]=b.w;
            float4 c = p2[k]; w2[4*k]=c.x; w2[4*k+1]=c.y; w2[4*k+2]=c.z; w2[4*k+3]=c.w;
        }
    }
    const float bias0 = b_ih[j] + b_hh[j];
    const float bias1 = b_ih[32 + j] + b_hh[32 + j];
    const float bias2 = b_ih[64 + j] + 0.f;

    for (int p = 0; p < 32; ++p) {
        const int r = wave * 64 + 2 * p + (lol ? 0 : 1);
        const float4* xr = (const float4*)(xt + r * 64);
        float a0 = bias0, a1 = bias1, a2 = bias2;
        float c0 = 0.f, c1 = 0.f, c2 = 0.f;
#pragma unroll
        for (int k = 0; k < 16; ++k) {
            float4 xv = xr[k];
            a0 = fmaf(w0[4*k],   xv.x, a0); c0 = fmaf(w0[4*k+1], xv.y, c0);
            a0 = fmaf(w0[4*k+2], xv.z, a0); c0 = fmaf(w0[4*k+3], xv.w, c0);
            a1 = fmaf(w1[4*k],   xv.x, a1); c1 = fmaf(w1[4*k+1], xv.y, c1);
            a1 = fmaf(w1[4*k+2], xv.z, a1); c1 = fmaf(w1[4*k+3], xv.w, c1);
            a2 = fmaf(w2[4*k],   xv.x, a2); c2 = fmaf(w2[4*k+1], xv.y, c2);
            a2 = fmaf(w2[4*k+2], xv.z, a2); c2 = fmaf(w2[4*k+3], xv.w, c2);
        }
        float* ob = gix + (row0 + r) * 96;
        float2 rn; rn.x = a0 + c0; rn.y = a2 + c2;      // (r_j, n_j)
        ((float2*)ob)[j] = rn;
        ob[64 + j] = a1 + c1;                           // z_j
    }
}

// ---------------- kernel 2: autoregressive loop (LDS-free) ----------------
// One wave per batch element. h kept as 32 uniform scalars (v_readlane gather).
// slot1: lo lanes r-row j, hi lanes z-row 32+j          (w_hh, K=32)
// slot2: lo lanes n-row 64+j, hi lanes j<5 fc-row j     (deferred FC: logits(h_{t-1}))
// Recurrent-path arithmetic: fp32 with ~1-1.5 ulp transcendentals (exp_cw/rcp_nr);
// softmax OUTPUT (non-feedback) uses __expf/__logf.
__global__ __launch_bounds__(64, 1)
void ar_fast(const float* __restrict__ w_ih,
             const float* __restrict__ w_hh,
             const float* __restrict__ b_ih,
             const float* __restrict__ b_hh,
             const float* __restrict__ fc_w,
             const float* __restrict__ fc_b,
             const float* __restrict__ emb,
             const float* __restrict__ gix,
             float* __restrict__ out) {
    const int lane = threadIdx.x;
    const int j = lane & 31;
    const bool lol = (lane < 32);
    const int b = blockIdx.x;

    // slot1 weights: lo -> w_hh row j (r), hi -> row 32+j (z)
    float w1[32];
    {
        const float4* ps = (const float4*)(w_hh + (size_t)(lol ? j : 32 + j) * 32);
#pragma unroll
        for (int k = 0; k < 8; ++k) {
            float4 a = ps[k];
            w1[4*k]=a.x; w1[4*k+1]=a.y; w1[4*k+2]=a.z; w1[4*k+3]=a.w;
        }
    }
    // slot2 weights: lo -> w_hh row 64+j (n), hi j<5 -> fc_w row j, else zeros
    float w2[32];
    float a2init;
    if (lol) {
        const float4* pn = (const float4*)(w_hh + (size_t)(64 + j) * 32);
#pragma unroll
        for (int k = 0; k < 8; ++k) {
            float4 a = pn[k];
            w2[4*k]=a.x; w2[4*k+1]=a.y; w2[4*k+2]=a.z; w2[4*k+3]=a.w;
        }
        a2init = b_hh[64 + j];
    } else if (j < 5) {
        const float4* pf = (const float4*)(fc_w + (size_t)j * 32);
#pragma unroll
        for (int k = 0; k < 8; ++k) {
            float4 a = pf[k];
            w2[4*k]=a.x; w2[4*k+1]=a.y; w2[4*k+2]=a.z; w2[4*k+3]=a.w;
        }
        a2init = fc_b[j];
    } else {
#pragma unroll
        for (int k = 0; k < 32; ++k) w2[k] = 0.f;
        a2init = 0.f;
    }

    // gp tables
    float p1t[5], p2t[5];
    {
        const float4* q1 = (const float4*)(w_ih + (size_t)(lol ? j : 32 + j) * 128 + 64);
        const float4* q2 = (const float4*)(w_ih + (size_t)(64 + j) * 128 + 64);
#pragma unroll
        for (int c = 0; c < 5; ++c) {
            const float4* e4 = (const float4*)(emb + (size_t)c * 64);
            float s1 = 0.f, t1 = 0.f, s2 = 0.f, t2 = 0.f;
#pragma unroll
            for (int k = 0; k < 16; ++k) {
                float4 e = e4[k];
                float4 a = q1[k];
                s1 = fmaf(a.x, e.x, s1); t1 = fmaf(a.y, e.y, t1);
                s1 = fmaf(a.z, e.z, s1); t1 = fmaf(a.w, e.w, t1);
                float4 d = q2[k];
                s2 = fmaf(d.x, e.x, s2); t2 = fmaf(d.y, e.y, t2);
                s2 = fmaf(d.z, e.z, s2); t2 = fmaf(d.w, e.w, t2);
            }
            p1t[c] = s1 + t1;
            p2t[c] = lol ? (s2 + t2) : 0.f;
        }
    }

    // state
    float sh[32];
#pragma unroll
    for (int k = 0; k < 32; ++k) sh[k] = 0.f;
    float h_reg = 0.f;
    int idx = -1;

    const float* gxp = gix + (size_t)b * TT * 96;
    float* outp = out + (size_t)b * TT * 5;

    const int loff = lol ? (2 * j) : (64 + (j & ~1));
    const bool zodd = (!lol) && (j & 1);
    const float* gq = gxp + loff;

    float2 q0  = *(const float2*)(gq + (size_t)0 * 96);
    float2 q1_ = *(const float2*)(gq + (size_t)1 * 96);
    float2 q2_ = *(const float2*)(gq + (size_t)2 * 96);
    float2 q3_ = *(const float2*)(gq + (size_t)3 * 96);

    auto STEP = [&](float2& q, int t) {
        // consume current slot, immediately issue refill for t+4
        const float qx = q.x, qy = q.y;
        const int tld = min(t + 4, TT - 1);
        q = *(const float2*)(gq + (size_t)tld * 96);

        // slot dots over uniform h_{t-1}
        float a1 = 0.f, c1 = 0.f, a2 = a2init, c2 = 0.f;
#pragma unroll
        for (int k = 0; k < 32; k += 2) {
            a1 = fmaf(w1[k],   sh[k],   a1); c1 = fmaf(w1[k+1], sh[k+1], c1);
            a2 = fmaf(w2[k],   sh[k],   a2); c2 = fmaf(w2[k+1], sh[k+1], c2);
        }
        const float gh1 = a1 + c1;   // lo: ghr ; hi: ghz
        const float gh2 = a2 + c2;   // lo: b_hh_n + ghn ; hi j<5: logits_{t-1}[j]

        // argmax for step t-1 (critical: feeds the gate adds via idx)
        float l0 = 0.f, l1 = 0.f, l2 = 0.f, l3 = 0.f, l4 = 0.f, m = 0.f;
        const bool wrout = (t > 0);
        if (wrout) {
            l0 = rdlane_f(gh2, 32);
            l1 = rdlane_f(gh2, 33);
            l2 = rdlane_f(gh2, 34);
            l3 = rdlane_f(gh2, 35);
            l4 = rdlane_f(gh2, 36);
            m = fmaxf(fmaxf(fmaxf(l0, l1), fmaxf(l2, l3)), l4);
            idx = (l0 == m) ? 0 : (l1 == m) ? 1 : (l2 == m) ? 2 : (l3 == m) ? 3 : 4;
        }
        const float p1 = (idx==0)?p1t[0]:(idx==1)?p1t[1]:(idx==2)?p1t[2]:(idx==3)?p1t[3]:(idx==4)?p1t[4]:0.f;
        const float p2 = (idx==0)?p2t[0]:(idx==1)?p2t[1]:(idx==2)?p2t[2]:(idx==3)?p2t[3]:(idx==4)?p2t[4]:0.f;

        const float g1 = lol ? qx : (zodd ? qy : qx);  // lo: gix r ; hi: gix z
        const float g2 = lol ? qy : 0.f;               // lo: gix n

        // GRU cell — branch-free ~1ulp transcendentals
        const float s1v = sigmoid_fast(g1 + p1 + gh1);  // lo: r ; hi: z
        const float zz = __shfl_xor(s1v, 32, 64);       // lo receives z
        const float nn = tanh_fast(g2 + p2 + s1v * gh2);
        const float hnew = (1.f - zz) * nn + zz * h_reg;
        h_reg = hnew;                                    // hi-lane value never read

        // gather h_t to uniform scalars
#pragma unroll
        for (int k = 0; k < 32; ++k) sh[k] = rdlane_f(hnew, k);

        // log-softmax OUTPUT for step t-1 (off the recurrent path; fills gather slack)
        if (wrout) {
            const float ssum = __expf(l0 - m) + __expf(l1 - m) + __expf(l2 - m)
                             + __expf(l3 - m) + __expf(l4 - m);
            const float lns = __logf(ssum);
            if (lane < 5) {
                const float lv = (lane == 0) ? l0 : (lane == 1) ? l1 : (lane == 2) ? l2
                               : (lane == 3) ? l3 : l4;
                outp[(size_t)(t - 1) * 5 + lane] = (lv - m) - lns;
            }
        }
    };

    for (int t = 0; t < TT; t += 4) {
        STEP(q0,  t);
        STEP(q1_, t + 1);
        STEP(q2_, t + 2);
        STEP(q3_, t + 3);
    }

    // tail: logits for t = TT-1 from final h
    {
        float a2 = a2init, c2 = 0.f;
#pragma unroll
        for (int k = 0; k < 32; k += 2) {
            a2 = fmaf(w2[k],   sh[k],   a2);
            c2 = fmaf(w2[k+1], sh[k+1], c2);
        }
        const float gh2 = a2 + c2;
        const float l0 = rdlane_f(gh2, 32);
        const float l1 = rdlane_f(gh2, 33);
        const float l2 = rdlane_f(gh2, 34);
        const float l3 = rdlane_f(gh2, 35);
        const float l4 = rdlane_f(gh2, 36);
        const float m = fmaxf(fmaxf(fmaxf(l0, l1), fmaxf(l2, l3)), l4);
        const float ssum = __expf(l0 - m) + __expf(l1 - m) + __expf(l2 - m)
                         + __expf(l3 - m) + __expf(l4 - m);
        const float lns = __logf(ssum);
        if (lane < 5) {
            const float lv = (lane == 0) ? l0 : (lane == 1) ? l1 : (lane == 2) ? l2
                           : (lane == 3) ? l3 : l4;
            outp[(size_t)(TT - 1) * 5 + lane] = (lv - m) - lns;
        }
    }
}

// ---------------- fallback (ws too small): round-2 MODE1, known-correct ----------------
__global__ __launch_bounds__(64)
void ar_fallback(const float* __restrict__ x,
                 const float* __restrict__ w_ih,
                 const float* __restrict__ w_hh,
                 const float* __restrict__ b_ih,
                 const float* __restrict__ b_hh,
                 const float* __restrict__ fc_w,
                 const float* __restrict__ fc_b,
                 const float* __restrict__ emb,
                 float* __restrict__ out) {
    __shared__ __align__(16) float hsh[32];
    __shared__ __align__(16) float xsh[2][64];
    const int lane = threadIdx.x;
    const int j = lane & 31;
    const int b = blockIdx.x;

    float wr_[32], wz_[32], wn_[32];
    {
        const float4* pr = (const float4*)(w_hh + (size_t)j * 32);
        const float4* pz = (const float4*)(w_hh + (size_t)(32 + j) * 32);
        const float4* pn = (const float4*)(w_hh + (size_t)(64 + j) * 32);
#pragma unroll
        for (int k = 0; k < 8; ++k) {
            float4 a = pr[k]; wr_[4*k]=a.x; wr_[4*k+1]=a.y; wr_[4*k+2]=a.z; wr_[4*k+3]=a.w;
            float4 c = pz[k]; wz_[4*k]=c.x; wz_[4*k+1]=c.y; wz_[4*k+2]=c.z; wz_[4*k+3]=c.w;
            float4 d = pn[k]; wn_[4*k]=d.x; wn_[4*k+1]=d.y; wn_[4*k+2]=d.z; wn_[4*k+3]=d.w;
        }
    }
    float fw[32]; float fb = 0.f;
    if (j < 5) {
        const float4* pf = (const float4*)(fc_w + (size_t)j * 32);
#pragma unroll
        for (int k = 0; k < 8; ++k) {
            float4 a = pf[k]; fw[4*k]=a.x; fw[4*k+1]=a.y; fw[4*k+2]=a.z; fw[4*k+3]=a.w;
        }
        fb = fc_b[j];
    } else {
#pragma unroll
        for (int k = 0; k < 32; ++k) fw[k] = 0.f;
    }
    float gpr[5], gpz[5], gpn[5];
    {
        const float4* qr = (const float4*)(w_ih + (size_t)j * 128 + 64);
        const float4* qz = (const float4*)(w_ih + (size_t)(32 + j) * 128 + 64);
        const float4* qn = (const float4*)(w_ih + (size_t)(64 + j) * 128 + 64);
#pragma unroll
        for (int c = 0; c < 5; ++c) {
            const float4* e4 = (const float4*)(emb + (size_t)c * 64);
            float sr = 0.f, sz = 0.f, sn = 0.f, tr = 0.f, tz = 0.f, tn = 0.f;
#pragma unroll
            for (int k = 0; k < 16; ++k) {
                float4 e = e4[k];
                float4 a = qr[k];
                sr = fmaf(a.x, e.x, sr); tr = fmaf(a.y, e.y, tr);
                sr = fmaf(a.z, e.z, sr); tr = fmaf(a.w, e.w, tr);
                float4 c2 = qz[k];
                sz = fmaf(c2.x, e.x, sz); tz = fmaf(c2.y, e.y, tz);
                sz = fmaf(c2.z, e.z, sz); tz = fmaf(c2.w, e.w, tz);
                float4 d = qn[k];
                sn = fmaf(d.x, e.x, sn); tn = fmaf(d.y, e.y, tn);
                sn = fmaf(d.z, e.z, sn); tn = fmaf(d.w, e.w, tn);
            }
            gpr[c] = sr + tr; gpz[c] = sz + tz; gpn[c] = sn + tn;
        }
    }
    const float bias_n = b_hh[64 + j];
    float wxr[64], wxz[64], wxn[64];
    float bxr, bxz, bxn;
    {
        const float4* qr = (const float4*)(w_ih + (size_t)j * 128);
        const float4* qz = (const float4*)(w_ih + (size_t)(32 + j) * 128);
        const float4* qn = (const float4*)(w_ih + (size_t)(64 + j) * 128);
#pragma unroll
        for (int k = 0; k < 16; ++k) {
            float4 a = qr[k]; wxr[4*k]=a.x; wxr[4*k+1]=a.y; wxr[4*k+2]=a.z; wxr[4*k+3]=a.w;
            float4 c = qz[k]; wxz[4*k]=c.x; wxz[4*k+1]=c.y; wxz[4*k+2]=c.z; wxz[4*k+3]=c.w;
            float4 d = qn[k]; wxn[4*k]=d.x; wxn[4*k+1]=d.y; wxn[4*k+2]=d.z; wxn[4*k+3]=d.w;
        }
        bxr = b_ih[j] + b_hh[j];
        bxz = b_ih[32 + j] + b_hh[32 + j];
        bxn = b_ih[64 + j];
    }

    if (lane < 32) hsh[j] = 0.f;
    float h_reg = 0.f;
    int idx = -1;
    const float* xgp = x + (size_t)b * TT * 64;
    float* outp = out + (size_t)b * TT * 5;
    xsh[0][lane] = xgp[lane];

    for (int t = 0; t < TT; ++t) {
        float xv_n = 0.f;
        if (t + 1 < TT) xv_n = xgp[(size_t)(t + 1) * 64 + lane];
        float hf[32];
        {
            const float4* h4 = (const float4*)hsh;
#pragma unroll
            for (int k = 0; k < 8; ++k) {
                float4 a = h4[k];
                hf[4*k]=a.x; hf[4*k+1]=a.y; hf[4*k+2]=a.z; hf[4*k+3]=a.w;
            }
        }
        float ar = 0.f, az = 0.f, an = bias_n;
        float br = 0.f, bz = 0.f, bn = 0.f;
#pragma unroll
        for (int k = 0; k < 32; k += 2) {
            ar = fmaf(wr_[k], hf[k], ar);   br = fmaf(wr_[k+1], hf[k+1], br);
            az = fmaf(wz_[k], hf[k], az);   bz = fmaf(wz_[k+1], hf[k+1], bz);
            an = fmaf(wn_[k], hf[k], an);   bn = fmaf(wn_[k+1], hf[k+1], bn);
        }
        const float ghr = ar + br, ghz = az + bz, ghn = an + bn;
        const float4* xb4 = (const float4*)(xsh[t & 1]);
        float ur = bxr, uz = bxz, un = bxn, vr = 0.f, vz = 0.f, vn = 0.f;
#pragma unroll
        for (int k = 0; k < 16; ++k) {
            float4 xv = xb4[k];
            ur = fmaf(wxr[4*k], xv.x, ur); vr = fmaf(wxr[4*k+1], xv.y, vr);
            ur = fmaf(wxr[4*k+2], xv.z, ur); vr = fmaf(wxr[4*k+3], xv.w, vr);
            uz = fmaf(wxz[4*k], xv.x, uz); vz = fmaf(wxz[4*k+1], xv.y, vz);
            uz = fmaf(wxz[4*k+2], xv.z, uz); vz = fmaf(wxz[4*k+3], xv.w, vz);
            un = fmaf(wxn[4*k], xv.x, un); vn = fmaf(wxn[4*k+1], xv.y, vn);
            un = fmaf(wxn[4*k+2], xv.z, un); vn = fmaf(wxn[4*k+3], xv.w, vn);
        }
        const float gr = ur + vr, gz = uz + vz, gn = un + vn;
        const float pr = (idx==0)?gpr[0]:(idx==1)?gpr[1]:(idx==2)?gpr[2]:(idx==3)?gpr[3]:(idx==4)?gpr[4]:0.f;
        const float pz = (idx==0)?gpz[0]:(idx==1)?gpz[1]:(idx==2)?gpz[2]:(idx==3)?gpz[3]:(idx==4)?gpz[4]:0.f;
        const float pn = (idx==0)?gpn[0]:(idx==1)?gpn[1]:(idx==2)?gpn[2]:(idx==3)?gpn[3]:(idx==4)?gpn[4]:0.f;
        const float r = 1.f / (1.f + expf(-(gr + pr + ghr)));
        const float z = 1.f / (1.f + expf(-(gz + pz + ghz)));
        const float n = tanhf(gn + pn + r * ghn);
        const float hnew = (1.f - z) * n + z * h_reg;
        if (lane < 32) hsh[j] = hnew;
        h_reg = hnew;
        float hg[32];
        {
            const float4* h4 = (const float4*)hsh;
#pragma unroll
            for (int k = 0; k < 8; ++k) {
                float4 a = h4[k];
                hg[4*k]=a.x; hg[4*k+1]=a.y; hg[4*k+2]=a.z; hg[4*k+3]=a.w;
            }
        }
        float la = fb, lb = 0.f;
#pragma unroll
        for (int k = 0; k < 32; k += 2) {
            la = fmaf(fw[k], hg[k], la);
            lb = fmaf(fw[k+1], hg[k+1], lb);
        }
        const float lg = la + lb;
        const float l0 = rdlane_f(lg, 0), l1 = rdlane_f(lg, 1), l2 = rdlane_f(lg, 2),
                    l3 = rdlane_f(lg, 3), l4 = rdlane_f(lg, 4);
        const float m = fmaxf(fmaxf(fmaxf(l0, l1), fmaxf(l2, l3)), l4);
        const float ssum = expf(l0-m)+expf(l1-m)+expf(l2-m)+expf(l3-m)+expf(l4-m);
        const float lns = logf(ssum);
        idx = (l0==m)?0:(l1==m)?1:(l2==m)?2:(l3==m)?3:4;
        if (lane < 5) {
            const float lv = (lane==0)?l0:(lane==1)?l1:(lane==2)?l2:(lane==3)?l3:l4;
            outp[(size_t)t * 5 + lane] = (lv - m) - lns;
        }
        if (t + 1 < TT) xsh[(t + 1) & 1][lane] = xv_n;
    }
}

extern "C" void kernel_launch(void* const* d_in, const int* in_sizes, int n_in,
                              void* d_out, int out_size, void* d_ws, size_t ws_size,
                              hipStream_t stream) {
    const float* x    = (const float*)d_in[0];
    const float* w_ih = (const float*)d_in[1];
    const float* w_hh = (const float*)d_in[2];
    const float* b_ih = (const float*)d_in[3];
    const float* b_hh = (const float*)d_in[4];
    const float* fc_w = (const float*)d_in[5];
    const float* fc_b = (const float*)d_in[6];
    const float* emb  = (const float*)d_in[7];
    float* out = (float*)d_out;

    const size_t GIX_BYTES = (size_t)BB * TT * 96 * sizeof(float);
    if (ws_size >= GIX_BYTES) {
        float* gix = (float*)d_ws;
        gix_fast<<<dim3((BB * TT) / 256), dim3(256), 0, stream>>>(x, w_ih, b_ih, b_hh, gix);
        ar_fast<<<dim3(BB), dim3(64), 0, stream>>>(w_ih, w_hh, b_ih, b_hh,
                                                   fc_w, fc_b, emb, gix, out);
    } else {
        ar_fallback<<<dim3(BB), dim3(64), 0, stream>>>(x, w_ih, w_hh, b_ih, b_hh,
                                                       fc_w, fc_b, emb, out);
    }
}